// Round 1
// 292.973 us; speedup vs baseline: 1.0118x; 1.0118x over previous
//
#include <hip/hip_runtime.h>
#include <stdint.h>

// Problem constants (fixed by the reference): x is (128,1,512,512) fp32, k=2048.
#define B        128
#define ROW_N    262144                 // 512*512 elements per row
#define THREADS  256
#define BLOCKS_PER_ROW 16
#define BLK_CHUNK (ROW_N / BLOCKS_PER_ROW)   // 16384 floats per block
#define WAVE_CHUNK 4096                      // floats per wave (4 waves/block)
#define WAVE_CAP 512                         // per-wave candidate cap (mean 184, +25 sigma)

// Speculative exact pre-filter: keep ALL elements with |x| >= 2.0.
// k-th |x| ~= 2.66 for the N(0,1) input; >=2.0 population ~11.9k +- 107 per row.
// n >= K guarantees the exact top-k lies within the candidate set. Any violation
// (per-wave cap, row cap, n < K, tie-bucket cap) -> exact in-block fallback.
#define B0_BITS  0x40000000u  // bit pattern of 2.0f (abs-bits compare)
#define CAND_CAP 16384        // per-row candidate capacity (+41 sigma)
#define FKSHIFT  17           // 14-bit fine key for tie resolution
#define FB0      8192         // (B0_BITS >> FKSHIFT)
#define NFB      8192         // fine buckets [8192, 16384)
#define TIE_CAP  2048         // ties in one fine bucket (mean ~190)
#define THREADS_SS 1024       // select block size (16 waves)
#define NWAVES_SS (THREADS_SS / 64)
// fallback histogram (coarse, full |x| range)
#define KSHIFT   19
#define NBUCKET  4096
#define FB_TIE_CAP 4096

// workspace layout (bytes)
#define OFF_CNT  0                         // per-row candidate counters (B u32)
#define OFF_OFL  512                       // per-row overflow flags (B u32)
#define OFF_CAND 4096                      // B * CAND_CAP * uint2 = 16 MiB
#define MEMSET_BYTES 1024

typedef float vfloat4 __attribute__((ext_vector_type(4)));

// ---- pass 0: pure-write zero fill of out ------------------------------------
// Unmixed from the read stream: 16 independent nontemporal float4 stores per
// thread (no vmcnt gating, no L3 pollution so x stays resident for the scan).
#define ZTHREADS 256
#define ZBLOCKS  2048
#define ZSTRIDE  (ZTHREADS * ZBLOCKS)          // 524288 threads
#define ZPT      ((B * ROW_N / 4) / ZSTRIDE)   // 16 float4 per thread

__global__ __launch_bounds__(ZTHREADS) void zero_kernel(float* __restrict__ out) {
    vfloat4* dst = (vfloat4*)out;
    const vfloat4 z = {0.f, 0.f, 0.f, 0.f};
    const unsigned tid = blockIdx.x * ZTHREADS + threadIdx.x;
#pragma unroll
    for (int i = 0; i < ZPT; ++i)
        __builtin_nontemporal_store(z, &dst[(size_t)i * ZSTRIDE + tid]);
}

// ---- pass A: pure-read scan + wave compaction of |x| >= 2.0 -----------------
// 8 float4 loads in flight per wave (vs 4 before; VGPR was 24 -> MLP-starved).
// No global stores except the tiny candidate flush (one atomic per wave).
__global__ __launch_bounds__(THREADS) void scan_compact_kernel(
        const float* __restrict__ x, unsigned* __restrict__ cand_count,
        unsigned* __restrict__ row_oflow, uint2* __restrict__ cand) {
    __shared__ uint2 wbuf[THREADS / 64][WAVE_CAP];   // 16 KiB, wave-private
    const int t = threadIdx.x;
    const int w = t >> 6;
    const int lane = t & 63;
    const unsigned long long lt = (1ull << lane) - 1ull;
    const int row = blockIdx.y;
    const int wbase = blockIdx.x * BLK_CHUNK + w * WAVE_CHUNK;  // float offset
    const float4* src = (const float4*)(x + (size_t)row * ROW_N + wbase);
    uint2* wb = wbuf[w];
    unsigned wcnt = 0;   // wave-uniform (derived from ballots only)

    for (int g = 0; g < 2; ++g) {
        float4 v[8];
#pragma unroll
        for (int u = 0; u < 8; ++u) v[u] = src[(g * 8 + u) * 64 + lane];
#pragma unroll
        for (int u = 0; u < 8; ++u) {
            const unsigned fbase = (unsigned)(wbase + ((g * 8 + u) * 64 + lane) * 4);
            const unsigned bb[4] = {__float_as_uint(v[u].x), __float_as_uint(v[u].y),
                                    __float_as_uint(v[u].z), __float_as_uint(v[u].w)};
#pragma unroll
            for (int c = 0; c < 4; ++c) {
                const bool pred = (bb[c] & 0x7FFFFFFFu) >= B0_BITS;   // ~4.5%
                const unsigned long long mask = __ballot(pred);
                if (pred) {
                    const unsigned p = wcnt + (unsigned)__popcll(mask & lt);
                    if (p < WAVE_CAP) wb[p] = make_uint2(fbase + (unsigned)c, bb[c]);
                }
                wcnt += (unsigned)__popcll(mask);
            }
        }
    }

    // final flush: one global atomic per wave
    const unsigned total = wcnt < WAVE_CAP ? wcnt : WAVE_CAP;
    unsigned base = 0;
    if (lane == 0) {
        base = atomicAdd(&cand_count[row], wcnt);   // true count (gap/oflow detect)
        if (wcnt > WAVE_CAP) row_oflow[row] = 1u;
    }
    base = __shfl(base, 0);
    uint2* rcand = cand + (size_t)row * CAND_CAP;
    for (unsigned i = (unsigned)lane; i < total; i += 64) {
        const unsigned gpos = base + i;
        if (gpos < CAND_CAP) rcand[gpos] = wb[i];
    }
}

// -- pass B: select+scatter, exact fallback FUSED into the same block ---------
// All fallback triggers are block-uniform and decided before any output write,
// so the block simply falls through to the exact solve (saves a kernel launch
// and the row_flag round-trip). Serial thread-0 scan replaced by a wave-shuffle
// block scan (6 shfl steps + 16 wave sums) — removes the ~512-step LDS chain.
__global__ __launch_bounds__(THREADS_SS) void select_scatter_kernel(
        const uint2* __restrict__ cand, const unsigned* __restrict__ cand_count,
        const unsigned* __restrict__ row_oflow, const int* __restrict__ topk,
        const float* __restrict__ x, float* __restrict__ out) {
    const int row = blockIdx.x;
    const int t = threadIdx.x;
    const int lane = t & 63;
    const int w = t >> 6;
    const unsigned K = (unsigned)(*topk);
    const unsigned n = cand_count[row];
    const unsigned of = row_oflow[row];
    float* rout = out + (size_t)row * ROW_N;

    // 48 KiB, aliased: fast path = h[NFB] + tidx/tbits[TIE_CAP];
    //                  fallback  = h[NBUCKET] + tidx/tbits[FB_TIE_CAP]. Both 12288 u32.
    __shared__ unsigned smem[NFB + 2 * TIE_CAP];
    __shared__ unsigned wsum[NWAVES_SS];
    __shared__ unsigned tcnt;
    __shared__ int sb, sneed;

    if (!(n < K || n > (unsigned)CAND_CAP || of)) {   // block-uniform
        // ---------------- fast path ----------------
        unsigned* h = smem;
        unsigned* tidx = smem + NFB;
        unsigned* tbits = smem + NFB + TIE_CAP;
        for (int i = t; i < NFB; i += THREADS_SS) h[i] = 0;
        if (t == 0) tcnt = 0;
        __syncthreads();

        const uint2* rc = cand + (size_t)row * CAND_CAP;
        for (unsigned i = (unsigned)t; i < n; i += THREADS_SS) {
            const uint2 e = rc[i];
            atomicAdd(&h[((e.y & 0x7FFFFFFFu) >> FKSHIFT) - FB0], 1u);
        }
        __syncthreads();

        // suffix counts: thread t owns PER buckets in descending order
        const int PER = NFB / THREADS_SS;   // 8
        unsigned s = 0;
#pragma unroll
        for (int i = 0; i < PER; ++i) s += h[NFB - 1 - (t * PER + i)];
        // block-wide exclusive scan over thread sums (wave shuffles + wave sums)
        unsigned v = s;
#pragma unroll
        for (int d = 1; d < 64; d <<= 1) {
            const unsigned o = __shfl_up(v, d);
            if (lane >= d) v += o;
        }
        if (lane == 63) wsum[w] = v;
        __syncthreads();
        unsigned cum = v - s;               // exclusive within wave
#pragma unroll
        for (int i = 0; i < NWAVES_SS; ++i) cum += (i < w) ? wsum[i] : 0u;
#pragma unroll
        for (int i = 0; i < PER; ++i) {
            const int brel = NFB - 1 - (t * PER + i);
            const unsigned c = h[brel];
            if (cum < K && cum + c >= K) {   // unique crossing
                sb = brel + FB0;
                sneed = (int)(K - cum);
            }
            cum += c;
        }
        __syncthreads();
        const int b = sb;
        const int need = sneed;
        if (h[b - FB0] <= (unsigned)TIE_CAP) {   // block-uniform; before any writes
            // scatter winners above the tie bucket; collect ties
            for (unsigned i = (unsigned)t; i < n; i += THREADS_SS) {
                const uint2 e = rc[i];
                const int fk = (int)((e.y & 0x7FFFFFFFu) >> FKSHIFT);
                if (fk > b) {
                    rout[e.x] = __uint_as_float(e.y);
                } else if (fk == b) {
                    const unsigned p = atomicAdd(&tcnt, 1u);
                    tidx[p] = e.x; tbits[p] = e.y;   // p < TIE_CAP by hist check
                }
            }
            __syncthreads();
            // exact rank among ties: desc |x| bits, asc index (matches lax.top_k)
            const int c = (int)tcnt;
            for (int i = t; i < c; i += THREADS_SS) {
                const unsigned bits = tbits[i], idx = tidx[i];
                const uint64_t key = ((uint64_t)(bits & 0x7FFFFFFFu) << 32) | (uint64_t)(~idx);
                int rank = 0;
                for (int j = 0; j < c; ++j) {
                    const uint64_t kj = ((uint64_t)(tbits[j] & 0x7FFFFFFFu) << 32) | (uint64_t)(~tidx[j]);
                    rank += (kj > key) ? 1 : 0;
                }
                if (rank < need) rout[idx] = __uint_as_float(bits);
            }
            return;
        }
        // tie-bucket overflow: fall through to exact fallback (nothing written yet)
    }

    // ---------------- exact fallback (normally never runs) ----------------
    __syncthreads();   // all threads done reading smem from the fast path
    {
        unsigned* h = smem;
        unsigned* tidx = smem + NBUCKET;
        unsigned* tbits = smem + NBUCKET + FB_TIE_CAP;
        for (int i = t; i < NBUCKET; i += THREADS_SS) h[i] = 0;
        if (t == 0) tcnt = 0;
        __syncthreads();

        const float4* xr = (const float4*)(x + (size_t)row * ROW_N);
        for (int i4 = t; i4 < ROW_N / 4; i4 += THREADS_SS) {
            const float4 v4 = xr[i4];
            atomicAdd(&h[(__float_as_uint(v4.x) & 0x7FFFFFFFu) >> KSHIFT], 1u);
            atomicAdd(&h[(__float_as_uint(v4.y) & 0x7FFFFFFFu) >> KSHIFT], 1u);
            atomicAdd(&h[(__float_as_uint(v4.z) & 0x7FFFFFFFu) >> KSHIFT], 1u);
            atomicAdd(&h[(__float_as_uint(v4.w) & 0x7FFFFFFFu) >> KSHIFT], 1u);
        }
        __syncthreads();

        const int PER = NBUCKET / THREADS_SS;   // 4
        unsigned s = 0;
#pragma unroll
        for (int i = 0; i < PER; ++i) s += h[NBUCKET - 1 - (t * PER + i)];
        unsigned v = s;
#pragma unroll
        for (int d = 1; d < 64; d <<= 1) {
            const unsigned o = __shfl_up(v, d);
            if (lane >= d) v += o;
        }
        if (lane == 63) wsum[w] = v;
        __syncthreads();
        unsigned cum = v - s;
#pragma unroll
        for (int i = 0; i < NWAVES_SS; ++i) cum += (i < w) ? wsum[i] : 0u;
#pragma unroll
        for (int i = 0; i < PER; ++i) {
            const int bucket = NBUCKET - 1 - (t * PER + i);
            const unsigned c = h[bucket];
            if (cum < K && cum + c >= K) { sb = bucket; sneed = (int)(K - cum); }
            cum += c;
        }
        __syncthreads();
        const int b = sb;
        const int need = sneed;

        for (int i4 = t; i4 < ROW_N / 4; i4 += THREADS_SS) {
            const float4 v4 = xr[i4];
            const unsigned bits4[4] = {__float_as_uint(v4.x), __float_as_uint(v4.y),
                                       __float_as_uint(v4.z), __float_as_uint(v4.w)};
#pragma unroll
            for (int c = 0; c < 4; ++c) {
                const int key = (int)((bits4[c] & 0x7FFFFFFFu) >> KSHIFT);
                if (key > b) {
                    rout[i4 * 4 + c] = __uint_as_float(bits4[c]);
                } else if (key == b) {
                    const unsigned p = atomicAdd(&tcnt, 1u);
                    if (p < FB_TIE_CAP) { tidx[p] = (unsigned)(i4 * 4 + c); tbits[p] = bits4[c]; }
                }
            }
        }
        __syncthreads();
        const int c = (int)(tcnt < (unsigned)FB_TIE_CAP ? tcnt : (unsigned)FB_TIE_CAP);
        for (int i = t; i < c; i += THREADS_SS) {
            const unsigned bits = tbits[i], idx = tidx[i];
            const uint64_t key = ((uint64_t)(bits & 0x7FFFFFFFu) << 32) | (uint64_t)(~idx);
            int rank = 0;
            for (int j = 0; j < c; ++j) {
                const uint64_t kj = ((uint64_t)(tbits[j] & 0x7FFFFFFFu) << 32) | (uint64_t)(~tidx[j]);
                rank += (kj > key) ? 1 : 0;
            }
            if (rank < need) rout[idx] = __uint_as_float(bits);
        }
    }
}

extern "C" void kernel_launch(void* const* d_in, const int* in_sizes, int n_in,
                              void* d_out, int out_size, void* d_ws, size_t ws_size,
                              hipStream_t stream) {
    const float* x = (const float*)d_in[0];
    const int* topk = (const int*)d_in[1];
    float* out = (float*)d_out;
    char* ws = (char*)d_ws;

    unsigned* cand_count = (unsigned*)(ws + OFF_CNT);
    unsigned* row_oflow  = (unsigned*)(ws + OFF_OFL);
    uint2* cand          = (uint2*)(ws + OFF_CAND);

    // zero counters + flags only (ws is re-poisoned to 0xAA before each run)
    hipMemsetAsync(ws, 0, MEMSET_BYTES, stream);

    // pure-write zero fill (unmixed from the read stream)
    zero_kernel<<<ZBLOCKS, ZTHREADS, 0, stream>>>(out);

    // pure-read scan + candidate compaction
    dim3 gridA(BLOCKS_PER_ROW, B);  // 16 x 128 = 2048 blocks, 8/CU
    scan_compact_kernel<<<gridA, THREADS, 0, stream>>>(x, cand_count, row_oflow, cand);

    // fused select + scatter + inline exact fallback
    select_scatter_kernel<<<B, THREADS_SS, 0, stream>>>(cand, cand_count, row_oflow,
                                                        topk, x, out);
}

// Round 2
// 255.084 us; speedup vs baseline: 1.1621x; 1.1485x over previous
//
#include <hip/hip_runtime.h>
#include <stdint.h>

// Problem constants (fixed by the reference): x is (128,1,512,512) fp32, k=2048.
#define B        128
#define ROW_N    262144                 // 512*512 elements per row
#define THREADS  256
#define BLOCKS_PER_ROW 16
#define BLK_CHUNK (ROW_N / BLOCKS_PER_ROW)   // 16384 floats per block
#define WAVE_CHUNK 4096                      // floats per wave (4 waves/block)

// Speculative exact pre-filter: keep ALL elements with |x| >= 2.5.
// k-th |x| ~= 2.66 for the N(0,1) input; >=2.5 population mean 3256, sigma 56.7
// per row -> n >= K at +21 sigma. n >= K guarantees the exact top-k lies in the
// candidate set. Any violation (segment cap, n < K, tie cap) -> exact fallback.
#define B0_BITS  0x40200000u  // bit pattern of 2.5f (abs-bits compare)
#define SEGS_PER_ROW 64       // 16 blocks x 4 waves, fixed segment per wave
#define SEGCAP   128          // entries per segment (mean 51, sigma 7.1, +10.7s)
#define FKSHIFT  17           // 14-bit fine key for tie resolution
#define FB0      8192         // (0x40000000 >> 17); keys here are >= 8196
#define NFB      8192         // fine buckets [8192, 16384)
#define TIE_CAP  2048         // ties in one fine bucket (mean ~190)
#define THREADS_SS 1024       // select block size (16 waves)
#define NWAVES_SS (THREADS_SS / 64)
// fallback histogram (coarse, full |x| range)
#define KSHIFT   19
#define NBUCKET  4096
#define FB_TIE_CAP 4096

// workspace layout (bytes); nothing needs pre-zeroing (counts are plain-stored
// by scan before select reads them; 0xAA poison elsewhere is never read).
#define OFF_WCNT 0                          // B * 64 u32 true per-wave counts
#define OFF_CAND 32768                      // B * 64 * SEGCAP * uint2 = 8 MiB

// ---- pass A: pure-read scan + wave compaction of |x| >= 2.5 -----------------
// 8 float4 loads in flight per wave; candidates go to a FIXED per-wave global
// segment (no atomics, no dependence on zeroed memory). True count is plain-
// stored; count > SEGCAP signals dropped entries -> select runs exact fallback.
__global__ __launch_bounds__(THREADS) void scan_compact_kernel(
        const float* __restrict__ x, unsigned* __restrict__ wcnt_arr,
        uint2* __restrict__ cand) {
    __shared__ uint2 wbuf[THREADS / 64][SEGCAP];   // 4 KiB, wave-private
    const int t = threadIdx.x;
    const int w = t >> 6;
    const int lane = t & 63;
    const unsigned long long lt = (1ull << lane) - 1ull;
    const int row = blockIdx.y;
    const int seg = blockIdx.x * (THREADS / 64) + w;            // 0..63
    const int wbase = blockIdx.x * BLK_CHUNK + w * WAVE_CHUNK;  // float offset
    const float4* src = (const float4*)(x + (size_t)row * ROW_N + wbase);
    uint2* wb = wbuf[w];
    unsigned wcnt = 0;   // wave-uniform (derived from ballots only)

    for (int g = 0; g < 2; ++g) {
        float4 v[8];
#pragma unroll
        for (int u = 0; u < 8; ++u) v[u] = src[(g * 8 + u) * 64 + lane];
#pragma unroll
        for (int u = 0; u < 8; ++u) {
            const unsigned fbase = (unsigned)(wbase + ((g * 8 + u) * 64 + lane) * 4);
            const unsigned bb[4] = {__float_as_uint(v[u].x), __float_as_uint(v[u].y),
                                    __float_as_uint(v[u].z), __float_as_uint(v[u].w)};
#pragma unroll
            for (int c = 0; c < 4; ++c) {
                const bool pred = (bb[c] & 0x7FFFFFFFu) >= B0_BITS;   // ~1.24%
                const unsigned long long mask = __ballot(pred);
                if (pred) {
                    const unsigned p = wcnt + (unsigned)__popcll(mask & lt);
                    if (p < SEGCAP) wb[p] = make_uint2(fbase + (unsigned)c, bb[c]);
                }
                wcnt += (unsigned)__popcll(mask);
            }
        }
    }

    // flush to the fixed segment; plain stores only
    const unsigned total = wcnt < SEGCAP ? wcnt : SEGCAP;
    uint2* rseg = cand + ((size_t)row * SEGS_PER_ROW + seg) * SEGCAP;
    for (unsigned i = (unsigned)lane; i < total; i += 64) rseg[i] = wb[i];
    if (lane == 0) wcnt_arr[row * SEGS_PER_ROW + seg] = wcnt;   // true count
}

// -- pass B: select+scatter; exact fallback fused (block-uniform triggers) ----
__global__ __launch_bounds__(THREADS_SS) void select_scatter_kernel(
        const uint2* __restrict__ cand, const unsigned* __restrict__ wcnt_arr,
        const int* __restrict__ topk, const float* __restrict__ x,
        float* __restrict__ out) {
    const int row = blockIdx.x;
    const int t = threadIdx.x;
    const int lane = t & 63;
    const int w = t >> 6;
    const unsigned K = (unsigned)(*topk);
    float* rout = out + (size_t)row * ROW_N;

    // 48 KiB, aliased: fast path = h[NFB] + tidx/tbits[TIE_CAP];
    //                  fallback  = h[NBUCKET] + tidx/tbits[FB_TIE_CAP]. Both 12288 u32.
    __shared__ unsigned smem[NFB + 2 * TIE_CAP];
    __shared__ unsigned cnt_s[SEGS_PER_ROW];
    __shared__ unsigned wsum[NWAVES_SS];
    __shared__ unsigned tcnt;
    __shared__ unsigned sn, sof;
    __shared__ int sb, sneed;

    if (t < SEGS_PER_ROW) cnt_s[t] = wcnt_arr[row * SEGS_PER_ROW + t];
    __syncthreads();
    if (w == 0) {   // wave 0: n = sum counts, oflow = any count > SEGCAP
        unsigned c = cnt_s[lane];
        unsigned o = (c > (unsigned)SEGCAP) ? 1u : 0u;
        unsigned ns = c;
#pragma unroll
        for (int d = 1; d < 64; d <<= 1) {
            ns += (unsigned)__shfl_xor((int)ns, d);
            o |= (unsigned)__shfl_xor((int)o, d);
        }
        if (lane == 0) { sn = ns; sof = o; }
    }
    __syncthreads();
    const unsigned n = sn;
    const unsigned of = sof;

    if (!(n < K || of)) {   // block-uniform
        // ---------------- fast path ----------------
        unsigned* h = smem;
        unsigned* tidx = smem + NFB;
        unsigned* tbits = smem + NFB + TIE_CAP;
        for (int i = t; i < NFB; i += THREADS_SS) h[i] = 0;
        if (t == 0) tcnt = 0;
        __syncthreads();

        // hist over candidates: wave w owns 4 contiguous segments (cnt ~51 < 64)
        const uint2* rc = cand + (size_t)row * SEGS_PER_ROW * SEGCAP;
#pragma unroll
        for (int j = 0; j < 4; ++j) {
            const int s = w * 4 + j;
            const unsigned c = cnt_s[s];
            for (unsigned i = (unsigned)lane; i < c; i += 64) {
                const uint2 e = rc[(size_t)s * SEGCAP + i];
                atomicAdd(&h[((e.y & 0x7FFFFFFFu) >> FKSHIFT) - FB0], 1u);
            }
        }
        __syncthreads();

        // suffix counts: thread t owns PER buckets in descending order
        const int PER = NFB / THREADS_SS;   // 8
        unsigned s = 0;
#pragma unroll
        for (int i = 0; i < PER; ++i) s += h[NFB - 1 - (t * PER + i)];
        // block-wide exclusive scan over thread sums (wave shuffles + wave sums)
        unsigned v = s;
#pragma unroll
        for (int d = 1; d < 64; d <<= 1) {
            const unsigned o2 = __shfl_up(v, d);
            if (lane >= d) v += o2;
        }
        if (lane == 63) wsum[w] = v;
        __syncthreads();
        unsigned cum = v - s;               // exclusive within wave
#pragma unroll
        for (int i = 0; i < NWAVES_SS; ++i) cum += (i < w) ? wsum[i] : 0u;
#pragma unroll
        for (int i = 0; i < PER; ++i) {
            const int brel = NFB - 1 - (t * PER + i);
            const unsigned c = h[brel];
            if (cum < K && cum + c >= K) {   // unique crossing
                sb = brel + FB0;
                sneed = (int)(K - cum);
            }
            cum += c;
        }
        __syncthreads();
        const int b = sb;
        const int need = sneed;
        if (h[b - FB0] <= (unsigned)TIE_CAP) {   // block-uniform; before any writes
            // scatter winners above the tie bucket; collect ties
#pragma unroll
            for (int j = 0; j < 4; ++j) {
                const int sgi = w * 4 + j;
                const unsigned c = cnt_s[sgi];
                for (unsigned i = (unsigned)lane; i < c; i += 64) {
                    const uint2 e = rc[(size_t)sgi * SEGCAP + i];
                    const int fk = (int)((e.y & 0x7FFFFFFFu) >> FKSHIFT);
                    if (fk > b) {
                        rout[e.x] = __uint_as_float(e.y);
                    } else if (fk == b) {
                        const unsigned p = atomicAdd(&tcnt, 1u);
                        tidx[p] = e.x; tbits[p] = e.y;   // p < TIE_CAP by hist check
                    }
                }
            }
            __syncthreads();
            // exact rank among ties: desc |x| bits, asc index (matches lax.top_k)
            const int c = (int)tcnt;
            for (int i = t; i < c; i += THREADS_SS) {
                const unsigned bits = tbits[i], idx = tidx[i];
                const uint64_t key = ((uint64_t)(bits & 0x7FFFFFFFu) << 32) | (uint64_t)(~idx);
                int rank = 0;
                for (int j = 0; j < c; ++j) {
                    const uint64_t kj = ((uint64_t)(tbits[j] & 0x7FFFFFFFu) << 32) | (uint64_t)(~tidx[j]);
                    rank += (kj > key) ? 1 : 0;
                }
                if (rank < need) rout[idx] = __uint_as_float(bits);
            }
            return;
        }
        // tie-bucket overflow: fall through to exact fallback (nothing written yet)
    }

    // ---------------- exact fallback (normally never runs) ----------------
    __syncthreads();   // all threads done reading smem from the fast path
    {
        unsigned* h = smem;
        unsigned* tidx = smem + NBUCKET;
        unsigned* tbits = smem + NBUCKET + FB_TIE_CAP;
        for (int i = t; i < NBUCKET; i += THREADS_SS) h[i] = 0;
        if (t == 0) tcnt = 0;
        __syncthreads();

        const float4* xr = (const float4*)(x + (size_t)row * ROW_N);
        for (int i4 = t; i4 < ROW_N / 4; i4 += THREADS_SS) {
            const float4 v4 = xr[i4];
            atomicAdd(&h[(__float_as_uint(v4.x) & 0x7FFFFFFFu) >> KSHIFT], 1u);
            atomicAdd(&h[(__float_as_uint(v4.y) & 0x7FFFFFFFu) >> KSHIFT], 1u);
            atomicAdd(&h[(__float_as_uint(v4.z) & 0x7FFFFFFFu) >> KSHIFT], 1u);
            atomicAdd(&h[(__float_as_uint(v4.w) & 0x7FFFFFFFu) >> KSHIFT], 1u);
        }
        __syncthreads();

        const int PER = NBUCKET / THREADS_SS;   // 4
        unsigned s = 0;
#pragma unroll
        for (int i = 0; i < PER; ++i) s += h[NBUCKET - 1 - (t * PER + i)];
        unsigned v = s;
#pragma unroll
        for (int d = 1; d < 64; d <<= 1) {
            const unsigned o2 = __shfl_up(v, d);
            if (lane >= d) v += o2;
        }
        if (lane == 63) wsum[w] = v;
        __syncthreads();
        unsigned cum = v - s;
#pragma unroll
        for (int i = 0; i < NWAVES_SS; ++i) cum += (i < w) ? wsum[i] : 0u;
#pragma unroll
        for (int i = 0; i < PER; ++i) {
            const int bucket = NBUCKET - 1 - (t * PER + i);
            const unsigned c = h[bucket];
            if (cum < K && cum + c >= K) { sb = bucket; sneed = (int)(K - cum); }
            cum += c;
        }
        __syncthreads();
        const int b = sb;
        const int need = sneed;

        for (int i4 = t; i4 < ROW_N / 4; i4 += THREADS_SS) {
            const float4 v4 = xr[i4];
            const unsigned bits4[4] = {__float_as_uint(v4.x), __float_as_uint(v4.y),
                                       __float_as_uint(v4.z), __float_as_uint(v4.w)};
#pragma unroll
            for (int c = 0; c < 4; ++c) {
                const int key = (int)((bits4[c] & 0x7FFFFFFFu) >> KSHIFT);
                if (key > b) {
                    rout[i4 * 4 + c] = __uint_as_float(bits4[c]);
                } else if (key == b) {
                    const unsigned p = atomicAdd(&tcnt, 1u);
                    if (p < FB_TIE_CAP) { tidx[p] = (unsigned)(i4 * 4 + c); tbits[p] = bits4[c]; }
                }
            }
        }
        __syncthreads();
        const int c = (int)(tcnt < (unsigned)FB_TIE_CAP ? tcnt : (unsigned)FB_TIE_CAP);
        for (int i = t; i < c; i += THREADS_SS) {
            const unsigned bits = tbits[i], idx = tidx[i];
            const uint64_t key = ((uint64_t)(bits & 0x7FFFFFFFu) << 32) | (uint64_t)(~idx);
            int rank = 0;
            for (int j = 0; j < c; ++j) {
                const uint64_t kj = ((uint64_t)(tbits[j] & 0x7FFFFFFFu) << 32) | (uint64_t)(~tidx[j]);
                rank += (kj > key) ? 1 : 0;
            }
            if (rank < need) rout[idx] = __uint_as_float(bits);
        }
    }
}

extern "C" void kernel_launch(void* const* d_in, const int* in_sizes, int n_in,
                              void* d_out, int out_size, void* d_ws, size_t ws_size,
                              hipStream_t stream) {
    const float* x = (const float*)d_in[0];
    const int* topk = (const int*)d_in[1];
    float* out = (float*)d_out;
    char* ws = (char*)d_ws;

    unsigned* wcnt_arr = (unsigned*)(ws + OFF_WCNT);
    uint2* cand        = (uint2*)(ws + OFF_CAND);

    // zero-fill out via the rocclr fill path (measured 5.97 TB/s on this box)
    hipMemsetAsync(out, 0, (size_t)B * ROW_N * sizeof(float), stream);

    // pure-read scan + fixed-segment candidate compaction (no atomics,
    // no pre-zeroed state required)
    dim3 gridA(BLOCKS_PER_ROW, B);  // 16 x 128 = 2048 blocks, 8/CU
    scan_compact_kernel<<<gridA, THREADS, 0, stream>>>(x, wcnt_arr, cand);

    // fused select + scatter + inline exact fallback
    select_scatter_kernel<<<B, THREADS_SS, 0, stream>>>(cand, wcnt_arr, topk, x, out);
}